// Round 5
// baseline (68394.312 us; speedup 1.0000x reference)
//
#include <hip/hip_runtime.h>
#include <math.h>

static constexpr int Tt  = 512;
static constexpr int INF = 256;
static constexpr int Hf  = 512;
static constexpr int OUTF = 10;
static constexpr int NBLK = 256;   // 128 state-blocks + 128 x-blocks
static constexpr int NTHR = 1024;  // 16 waves
static constexpr unsigned SMEM_BYTES = 81920; // 53248 used; padded to force 1 block/CU

__device__ __forceinline__ float sigmoidf_(float x) {
    return 1.0f / (1.0f + __expf(-x));
}
__device__ __forceinline__ float tanhf_(float x) {
    float e = __expf(-2.0f * fabsf(x));
    float r = (1.0f - e) / (1.0f + e);
    return copysignf(r, x);
}

// Agent-scope relaxed scalar access (cache-served, coherent at LLC; 4-byte ONLY —
// 8-byte atomics bypass caches and stream from HBM: round-4 regression).
__device__ __forceinline__ float ldc(const float* p) {
    return __hip_atomic_load(const_cast<float*>(p), __ATOMIC_RELAXED, __HIP_MEMORY_SCOPE_AGENT);
}
__device__ __forceinline__ void stc(float* p, float v) {
    __hip_atomic_store(p, v, __ATOMIC_RELAXED, __HIP_MEMORY_SCOPE_AGENT);
}

// Grid barrier (flag array, round-3-proven semantics).
__device__ __forceinline__ void arrive_(unsigned* flags, unsigned gen) {
    __syncthreads();   // drains vmcnt per wave -> all stc stores at coherence point
    if (threadIdx.x == 0)
        __hip_atomic_store(&flags[blockIdx.x], gen, __ATOMIC_RELAXED, __HIP_MEMORY_SCOPE_AGENT);
}
__device__ __forceinline__ void wait_(unsigned* flags, unsigned gen) {
    if (threadIdx.x < NBLK) {
        unsigned* f = &flags[threadIdx.x];
        while (__hip_atomic_load(f, __ATOMIC_RELAXED, __HIP_MEMORY_SCOPE_AGENT) < gen)
            __builtin_amdgcn_s_sleep(1);
    }
    __syncthreads();
}

// x (B,T,IN) -> xT (T,IN,B)
__global__ __launch_bounds__(256) void transpose_x_k(const float* __restrict__ x,
                                                     float* __restrict__ xT) {
    __shared__ float tile[64][65];
    int t  = blockIdx.x;
    int k0 = blockIdx.y * 64;
    int tid = threadIdx.x;
#pragma unroll
    for (int i = 0; i < 16; ++i) {
        int idx = i * 256 + tid;
        int bb = idx >> 6, kk = idx & 63;
        tile[bb][kk] = x[(size_t)bb * Tt * INF + (size_t)t * INF + k0 + kk];
    }
    __syncthreads();
#pragma unroll
    for (int i = 0; i < 16; ++i) {
        int idx = i * 256 + tid;
        int kk = idx >> 6, bb = idx & 63;
        xT[(size_t)t * INF * 64 + (size_t)(k0 + kk) * 64 + bb] = tile[bb][kk];
    }
}

#define FMA4(a, w, v) { (a).x = fmaf((w).x, (v), (a).x); (a).y = fmaf((w).y, (v), (a).y); \
                        (a).z = fmaf((w).z, (v), (a).z); (a).w = fmaf((w).w, (v), (a).w); }

// x-block window: GEMV of 1-2 x-matrices (4 cols) for one time slice -> XP slot.
// Weight loads are wave-uniform float4 (scalar path); x loads coalesced per lane.
template<int LIN>
__device__ __forceinline__ void xwin(const float* __restrict__ xs,
                                     const float4* __restrict__ wA,
                                     const float4* __restrict__ wB,
                                     float4* pb4, float* pb,
                                     int ma, int mb, float* XPs, int c0) {
    const int tid = threadIdx.x, lane = tid & 63, wv = tid >> 6;
    constexpr int CX = LIN / 16;
    float4 aA = {0, 0, 0, 0}, aB = {0, 0, 0, 0};
    const float* xb = xs + lane;
    const int kk0 = wv * CX;
#pragma unroll 8
    for (int k = kk0; k < kk0 + CX; ++k) {
        float xv = xb[(size_t)k * 64];
        float4 w = wA[(size_t)k * 128]; FMA4(aA, w, xv);
        if (mb >= 0) { w = wB[(size_t)k * 128]; FMA4(aB, w, xv); }
    }
    __syncthreads();                       // pb free (previous window's readers done)
    pb4[(0 * 16 + wv) * 64 + lane] = aA;
    if (mb >= 0) pb4[(1 * 16 + wv) * 64 + lane] = aB;
    __syncthreads();
    const int nm = (mb >= 0) ? 2 : 1;
    if (tid < nm * 256) {
        int m = tid >> 8, rem = tid & 255, c = rem >> 6, b = rem & 63;
        float s = 0.f;
#pragma unroll
        for (int w = 0; w < 16; ++w) s += pb[((m * 16 + w) * 64 + b) * 4 + c];
        int mat = (m == 0) ? ma : mb;
        stc(&XPs[((size_t)mat * 512 + c0 + c) * 64 + b], s);
    }
}

// Persistent layer kernel. Blocks 0-127: state GEMVs (4 cols x 64 batches).
// Blocks 128-255: x-projections for step t+1 (5 mats) into XP ping-pong.
// 1 prologue barrier + 3 barriers/step. XP[slot][mat][512][64].
template<int LIN, bool WRITE_Y>
__global__ __launch_bounds__(NTHR) void esn_persist_k(
    const float* __restrict__ xT, float* __restrict__ y,
    float* rA, float* rB, float* hA, float* hB,
    float* rhB, float* hgB, float* XP,
    const float* __restrict__ Win, const float* __restrict__ Wres,
    const float* __restrict__ Wz, const float* __restrict__ bz,
    const float* __restrict__ Wr, const float* __restrict__ br,
    const float* __restrict__ Wc, const float* __restrict__ bc,
    const float* __restrict__ Wg, const float* __restrict__ bg,
    const float* __restrict__ Wp, const float* __restrict__ bp,
    unsigned* flags)
{
    extern __shared__ char smem[];
    const int tid = threadIdx.x, lane = tid & 63, wv = tid >> 6;
    unsigned gen = 0;
    constexpr size_t MSZ = (size_t)512 * 64;   // one [512][64] matrix of XP

    if (blockIdx.x < 128) {
        // ================= state block =================
        const int c0 = blockIdx.x * 4;
        float4* pb4 = (float4*)smem;               // [3][16][64] float4
        float*  pb  = (float*)pb4;
        float*  lz  = (float*)(pb4 + 3 * 16 * 64); // [4][64] locals
        float*  lhg = lz + 256;
        float*  lp  = lhg + 256;
        float*  lgg = lp + 256;

        // wave-uniform weight bases (4 cols each), row stride 128 float4s
        const float4* wres4 = (const float4*)(Wres + c0);
        const float4* wz4   = (const float4*)(Wz + (size_t)LIN * 512 + c0);
        const float4* wr4   = (const float4*)(Wr + (size_t)LIN * 512 + c0);
        const float4* wc4   = (const float4*)(Wc + (size_t)LIN * 512 + c0);
        const float4* wp4   = (const float4*)(Wp + c0);
        const float4* wgr4  = (const float4*)(Wg + (size_t)(LIN + 512) * 512 + c0);
        const float4* wgh4  = (const float4*)(Wg + (size_t)LIN * 512 + c0);

        // reduce-thread identity
        const int rm = tid >> 8, rrem = tid & 255, rcd = rrem >> 6, rb = rrem & 63;
        const int cab = c0 + rcd;
        const int gi  = cab * 64 + rb;
        const int k0  = wv * 32;

        arrive_(flags, ++gen); wait_(flags, gen);   // gen=1: XP slot0 ready (t=0)

        float *rc = rA, *rn = rB, *hc = hA, *hn = hB;

        for (int t = 0; t < Tt; ++t) {
            const float* XPt = XP + (size_t)(t & 1) * 5 * MSZ;

            // ---------- phase A: r_new, z, rh ----------
            {
                float pfx = 0.f, pfo = 0.f;
                if (tid < 768) {       // prefetch reduce operands (hidden under GEMV)
                    if (rm == 0)      { pfx = ldc(XPt + gi);            pfo = ldc(rc + gi); }
                    else if (rm == 1) { pfx = ldc(XPt + 1 * MSZ + gi); }
                    else              { pfx = ldc(XPt + 2 * MSZ + gi); pfo = ldc(hc + gi); }
                }
                float4 aRES = {0,0,0,0}, aZ = {0,0,0,0}, aRr = {0,0,0,0};
                const float* rcb = rc + lane;
                const float* hcb = hc + lane;
#pragma unroll 8
                for (int k = k0; k < k0 + 32; ++k) {
                    float rv = ldc(rcb + (size_t)k * 64);
                    float hv = ldc(hcb + (size_t)k * 64);
                    float4 w;
                    w = wres4[(size_t)k * 128]; FMA4(aRES, w, rv);
                    w = wz4[(size_t)k * 128];   FMA4(aZ, w, hv);
                    w = wr4[(size_t)k * 128];   FMA4(aRr, w, hv);
                }
                pb4[(0 * 16 + wv) * 64 + lane] = aRES;
                pb4[(1 * 16 + wv) * 64 + lane] = aZ;
                pb4[(2 * 16 + wv) * 64 + lane] = aRr;
                __syncthreads();
                if (tid < 768) {
                    float s = 0.f;
#pragma unroll
                    for (int w = 0; w < 16; ++w) s += pb[((rm * 16 + w) * 64 + rb) * 4 + rcd];
                    if (rm == 0) {
                        stc(rn + gi, 0.7f * pfo + 0.3f * tanhf_(s + pfx));
                    } else if (rm == 1) {
                        lz[rrem] = sigmoidf_(s + pfx + bz[cab]);
                    } else {
                        stc(rhB + gi, sigmoidf_(s + pfx + br[cab]) * pfo);
                    }
                }
                arrive_(flags, ++gen); wait_(flags, gen);
            }

            // ---------- phase B: h_gru, p, gg ----------
            {
                float pfx = 0.f, pfo = 0.f;
                if (tid < 768) {
                    if (rm == 0)      { pfx = ldc(XPt + 3 * MSZ + gi); pfo = ldc(hc + gi); }
                    else if (rm == 2) { pfx = ldc(XPt + 4 * MSZ + gi); }
                }
                float4 aC = {0,0,0,0}, aP = {0,0,0,0}, aGr = {0,0,0,0};
                const float* rhb = rhB + lane;
                const float* rnb = rn + lane;
#pragma unroll 8
                for (int k = k0; k < k0 + 32; ++k) {
                    float rhv = ldc(rhb + (size_t)k * 64);
                    float rnv = ldc(rnb + (size_t)k * 64);
                    float4 w;
                    w = wc4[(size_t)k * 128];  FMA4(aC, w, rhv);
                    w = wp4[(size_t)k * 128];  FMA4(aP, w, rnv);
                    w = wgr4[(size_t)k * 128]; FMA4(aGr, w, rnv);
                }
                pb4[(0 * 16 + wv) * 64 + lane] = aC;
                pb4[(1 * 16 + wv) * 64 + lane] = aP;
                pb4[(2 * 16 + wv) * 64 + lane] = aGr;
                __syncthreads();
                if (tid < 768) {
                    float s = 0.f;
#pragma unroll
                    for (int w = 0; w < 16; ++w) s += pb[((rm * 16 + w) * 64 + rb) * 4 + rcd];
                    if (rm == 0) {
                        float cand = tanhf_(s + pfx + bc[cab]);
                        float zv = lz[rrem];
                        float hg = (1.f - zv) * pfo + zv * cand;
                        stc(hgB + gi, hg);
                        lhg[rrem] = hg;
                    } else if (rm == 1) {
                        lp[rrem] = tanhf_(s + bp[cab]);
                    } else {
                        lgg[rrem] = s + pfx;
                    }
                }
                arrive_(flags, ++gen); wait_(flags, gen);
            }

            // ---------- phase C: g, h_new ----------
            {
                float4 aGh = {0,0,0,0};
                const float* hgb = hgB + lane;
#pragma unroll 8
                for (int k = k0; k < k0 + 32; ++k) {
                    float hgv = ldc(hgb + (size_t)k * 64);
                    float4 w = wgh4[(size_t)k * 128];
                    FMA4(aGh, w, hgv);
                }
                pb4[(0 * 16 + wv) * 64 + lane] = aGh;
                __syncthreads();
                if (tid < 256) {
                    float s = 0.f;
#pragma unroll
                    for (int w = 0; w < 16; ++w) s += pb[(w * 64 + rb) * 4 + rcd];
                    float g = sigmoidf_(s + lgg[rrem] + bg[cab]);
                    float hnv = (1.f - g) * lhg[rrem] + g * lp[rrem];
                    stc(hn + gi, hnv);
                    if (WRITE_Y) y[(size_t)t * (512 * 64) + gi] = hnv;
                }
                arrive_(flags, ++gen); wait_(flags, gen);
            }

            float* tp = rc; rc = rn; rn = tp;
            tp = hc; hc = hn; hn = tp;
        }
    } else {
        // ================= x block =================
        const int c0 = (blockIdx.x - 128) * 4;
        float4* pb4 = (float4*)smem;    // [2][16][64] float4
        float*  pb  = (float*)pb4;

        const float4* w0 = (const float4*)(Win + c0);   // xres
        const float4* w1 = (const float4*)(Wz + c0);    // xz
        const float4* w2 = (const float4*)(Wr + c0);    // xr
        const float4* w3 = (const float4*)(Wc + c0);    // xc
        const float4* w4 = (const float4*)(Wg + c0);    // xgx

        float* XP0 = XP;

        // prologue: all 5 mats for t=0 into slot 0
        xwin<LIN>(xT, w0, w1, pb4, pb, 0, 1, XP0, c0);
        xwin<LIN>(xT, w2, w3, pb4, pb, 2, 3, XP0, c0);
        xwin<LIN>(xT, w4, w4, pb4, pb, 4, -1, XP0, c0);
        arrive_(flags, ++gen); wait_(flags, gen);

        for (int t = 0; t < Tt; ++t) {
            float* XPn = XP + (size_t)((t + 1) & 1) * 5 * MSZ;
            const float* xs = xT + (size_t)(t + 1) * LIN * 64;
            const bool go = (t + 1 < Tt);
            if (go) xwin<LIN>(xs, w1, w2, pb4, pb, 1, 2, XPn, c0);   // A window
            arrive_(flags, ++gen); wait_(flags, gen);
            if (go) xwin<LIN>(xs, w0, w4, pb4, pb, 0, 4, XPn, c0);   // B window
            arrive_(flags, ++gen); wait_(flags, gen);
            if (go) xwin<LIN>(xs, w3, w3, pb4, pb, 3, -1, XPn, c0);  // C window
            arrive_(flags, ++gen); wait_(flags, gen);
        }
    }
}

// Head: hid = relu(last@Wo1 + bo1)
__global__ __launch_bounds__(256) void head1_k(const float* __restrict__ hlast,
                                               const float* __restrict__ Wo1,
                                               const float* __restrict__ bo1,
                                               float* __restrict__ hidT) {
    int tid = threadIdx.x;
    int b = tid & 63, jg = tid >> 6;
    int j0 = blockIdx.x * 16 + jg * 4;
    float acc[4] = {0.f, 0.f, 0.f, 0.f};
    const float* ap = hlast + b;
    const float* wp = Wo1 + j0;
#pragma unroll 4
    for (int k = 0; k < Hf; ++k) {
        float xv = ap[k * 64];
        const float4 w = *reinterpret_cast<const float4*>(wp + k * 512);
        acc[0] = fmaf(w.x, xv, acc[0]);
        acc[1] = fmaf(w.y, xv, acc[1]);
        acc[2] = fmaf(w.z, xv, acc[2]);
        acc[3] = fmaf(w.w, xv, acc[3]);
    }
#pragma unroll
    for (int jj = 0; jj < 4; ++jj) {
        int j = j0 + jj;
        hidT[j * 64 + b] = fmaxf(acc[jj] + bo1[j], 0.f);
    }
}

__global__ __launch_bounds__(640) void head2_k(const float* __restrict__ hidT,
                                               const float* __restrict__ Wo2,
                                               const float* __restrict__ bo2,
                                               float* __restrict__ out) {
    int tid = threadIdx.x;
    if (tid >= 64 * OUTF) return;
    int b = tid / OUTF, o = tid % OUTF;
    float acc = 0.f;
    for (int k = 0; k < Hf; ++k)
        acc = fmaf(hidT[k * 64 + b], Wo2[k * OUTF + o], acc);
    out[tid] = acc + bo2[o];
}

struct LayerW {
    const float *Win, *Wres, *Wz, *bz, *Wr, *br, *Wc, *bc, *Wg, *bg, *Wp, *bp;
};

extern "C" void kernel_launch(void* const* d_in, const int* in_sizes, int n_in,
                              void* d_out, int out_size, void* d_ws, size_t ws_size,
                              hipStream_t stream) {
    const float* x = (const float*)d_in[0];
    LayerW L[2];
    int idx = 1;
    for (int li = 0; li < 2; ++li) {
        L[li].Win  = (const float*)d_in[idx++];
        L[li].Wres = (const float*)d_in[idx++];
        L[li].Wz   = (const float*)d_in[idx++];
        L[li].bz   = (const float*)d_in[idx++];
        L[li].Wr   = (const float*)d_in[idx++];
        L[li].br   = (const float*)d_in[idx++];
        L[li].Wc   = (const float*)d_in[idx++];
        L[li].bc   = (const float*)d_in[idx++];
        L[li].Wg   = (const float*)d_in[idx++];
        L[li].bg   = (const float*)d_in[idx++];
        L[li].Wp   = (const float*)d_in[idx++];
        L[li].bp   = (const float*)d_in[idx++];
    }
    const float* Wo1 = (const float*)d_in[idx++];
    const float* bo1 = (const float*)d_in[idx++];
    const float* Wo2 = (const float*)d_in[idx++];
    const float* bo2 = (const float*)d_in[idx++];

    char* ws = (char*)d_ws;
    size_t off = 0;
    auto walloc = [&](size_t bytes) -> float* {
        float* p = (float*)(ws + off);
        off += (bytes + 255) & ~(size_t)255;
        return p;
    };
    const size_t STATE = (size_t)Hf * 64 * sizeof(float); // 128 KiB
    float* xT0 = walloc((size_t)Tt * INF * 64 * sizeof(float)); // 33.5 MB
    float* y0  = walloc((size_t)Tt * Hf * 64 * sizeof(float));  // 67 MB
    float* rA  = walloc(STATE);
    float* rB  = walloc(STATE);
    float* hA  = walloc(STATE);
    float* hB  = walloc(STATE);
    float* rhB = walloc(STATE);
    float* hgB = walloc(STATE);
    float* hidT = walloc(STATE);
    float* XP  = walloc((size_t)2 * 5 * 512 * 64 * sizeof(float)); // 1.3 MB
    unsigned* flags = (unsigned*)walloc(NBLK * sizeof(unsigned));
    (void)ws_size;

    hipFuncSetAttribute((const void*)esn_persist_k<INF, true>,
                        hipFuncAttributeMaxDynamicSharedMemorySize, SMEM_BYTES);
    hipFuncSetAttribute((const void*)esn_persist_k<Hf, false>,
                        hipFuncAttributeMaxDynamicSharedMemorySize, SMEM_BYTES);

    transpose_x_k<<<dim3(Tt, INF / 64), 256, 0, stream>>>(x, xT0);

    // ---- layer 0
    hipMemsetAsync(flags, 0, NBLK * sizeof(unsigned), stream);
    hipMemsetAsync(rA, 0, STATE, stream);
    hipMemsetAsync(hA, 0, STATE, stream);
    esn_persist_k<INF, true><<<NBLK, NTHR, SMEM_BYTES, stream>>>(
        xT0, y0, rA, rB, hA, hB, rhB, hgB, XP,
        L[0].Win, L[0].Wres, L[0].Wz, L[0].bz, L[0].Wr, L[0].br,
        L[0].Wc, L[0].bc, L[0].Wg, L[0].bg, L[0].Wp, L[0].bp, flags);

    // ---- layer 1
    hipMemsetAsync(flags, 0, NBLK * sizeof(unsigned), stream);
    hipMemsetAsync(rA, 0, STATE, stream);
    hipMemsetAsync(hA, 0, STATE, stream);
    esn_persist_k<Hf, false><<<NBLK, NTHR, SMEM_BYTES, stream>>>(
        y0, nullptr, rA, rB, hA, hB, rhB, hgB, XP,
        L[1].Win, L[1].Wres, L[1].Wz, L[1].bz, L[1].Wr, L[1].br,
        L[1].Wc, L[1].bc, L[1].Wg, L[1].bg, L[1].Wp, L[1].bp, flags);

    // 512 steps (even) -> final h is back in hA.
    head1_k<<<dim3(32, 1), 256, 0, stream>>>(hA, Wo1, bo1, hidT);
    head2_k<<<dim3(1, 1), 640, 0, stream>>>(hidT, Wo2, bo2, (float*)d_out);
}

// Round 6
// 63465.771 us; speedup vs baseline: 1.0777x; 1.0777x over previous
//
#include <hip/hip_runtime.h>
#include <math.h>

static constexpr int Tt   = 512;
static constexpr int INF  = 256;
static constexpr int Hf   = 512;
static constexpr int OUTF = 10;
static constexpr int NBLK = 256;   // 128 layer-0 blocks + 128 layer-1 blocks
static constexpr int NTHR = 1024;  // 16 waves
static constexpr int SGLOB = Tt + 2;           // layer-1 trails by 2 steps
static constexpr unsigned SMEM_BYTES = 98304 + 49152 + 4096; // weights + pb + locals = 151552

__device__ __forceinline__ float sigmoidf_(float x) {
    return 1.0f / (1.0f + __expf(-x));
}
__device__ __forceinline__ float tanhf_(float x) {
    float e = __expf(-2.0f * fabsf(x));
    float r = (1.0f - e) / (1.0f + e);
    return copysignf(r, x);
}

// 4-byte scope-coherent store (write-through to LLC; never dirties L2).
__device__ __forceinline__ void stc(float* p, float v) {
    __hip_atomic_store(p, v, __ATOMIC_RELAXED, __HIP_MEMORY_SCOPE_AGENT);
}
__device__ __forceinline__ unsigned ldflag(const unsigned* p) {
    return __hip_atomic_load(const_cast<unsigned*>(p), __ATOMIC_RELAXED, __HIP_MEMORY_SCOPE_AGENT);
}

// Acquire fence: invalidate L1/L2 so subsequent NORMAL loads see LLC state.
// (All cross-block writes are write-through stc, so nothing dirty exists.)
__device__ __forceinline__ void fence_acq() {
    __builtin_amdgcn_fence(__ATOMIC_ACQUIRE, "agent");
}

// Grid barrier: arrive (drain stores -> block barrier -> flag), wait (poll all flags).
__device__ __forceinline__ void arrive_(unsigned* flags, unsigned gen) {
    asm volatile("s_waitcnt vmcnt(0)" ::: "memory");
    __syncthreads();
    if (threadIdx.x == 0)
        __hip_atomic_store(&flags[blockIdx.x], gen, __ATOMIC_RELAXED, __HIP_MEMORY_SCOPE_AGENT);
}
__device__ __forceinline__ void wait_(unsigned* flags, unsigned gen) {
    if (threadIdx.x < NBLK) {
        const unsigned* f = &flags[threadIdx.x];
        while (ldflag(f) < gen) __builtin_amdgcn_s_sleep(1);
    }
    __syncthreads();
}

// x (B,T,IN) -> xT (T,IN,B)
__global__ __launch_bounds__(256) void transpose_x_k(const float* __restrict__ x,
                                                     float* __restrict__ xT) {
    __shared__ float tile[64][65];
    int t  = blockIdx.x;
    int k0 = blockIdx.y * 64;
    int tid = threadIdx.x;
#pragma unroll
    for (int i = 0; i < 16; ++i) {
        int idx = i * 256 + tid;
        int bb = idx >> 6, kk = idx & 63;
        tile[bb][kk] = x[(size_t)bb * Tt * INF + (size_t)t * INF + k0 + kk];
    }
    __syncthreads();
#pragma unroll
    for (int i = 0; i < 16; ++i) {
        int idx = i * 256 + tid;
        int kk = idx >> 6, bb = idx & 63;
        xT[(size_t)t * INF * 64 + (size_t)(k0 + kk) * 64 + bb] = tile[bb][kk];
    }
}

#define FMA4(a, w, v) { (a).x = fmaf((w).x, (v), (a).x); (a).y = fmaf((w).y, (v), (a).y); \
                        (a).z = fmaf((w).z, (v), (a).z); (a).w = fmaf((w).w, (v), (a).w); }

// x-projection windows: per-wave k-slice, LDS weight broadcast, register carries.
__device__ __forceinline__ void xw1(const float* xs, int lane, int wv, int lin16,
                                    const float4* w0, float4& a0) {
    const int ke = wv * lin16 + lin16;
#pragma unroll 8
    for (int k = wv * lin16; k < ke; ++k) {
        float xv = xs[(size_t)k * 64 + lane];
        float4 w = w0[k]; FMA4(a0, w, xv);
    }
}
__device__ __forceinline__ void xw2(const float* xs, int lane, int wv, int lin16,
                                    const float4* w0, const float4* w1,
                                    float4& a0, float4& a1) {
    const int ke = wv * lin16 + lin16;
#pragma unroll 8
    for (int k = wv * lin16; k < ke; ++k) {
        float xv = xs[(size_t)k * 64 + lane];
        float4 w = w0[k]; FMA4(a0, w, xv);
        w = w1[k];        FMA4(a1, w, xv);
    }
}
__device__ __forceinline__ void xw3(const float* xs, int lane, int wv, int lin16,
                                    const float4* w0, const float4* w1, const float4* w2,
                                    float4& a0, float4& a1, float4& a2) {
    const int ke = wv * lin16 + lin16;
#pragma unroll 8
    for (int k = wv * lin16; k < ke; ++k) {
        float xv = xs[(size_t)k * 64 + lane];
        float4 w = w0[k]; FMA4(a0, w, xv);
        w = w1[k];        FMA4(a1, w, xv);
        w = w2[k];        FMA4(a2, w, xv);
    }
}

struct KParams {
    const float* xT0;
    float* y0;
    const float *Win0,*Wres0,*Wz0,*bz0,*Wr0,*br0,*Wc0,*bc0,*Wg0,*bg0,*Wp0,*bp0;
    const float *Win1,*Wres1,*Wz1,*bz1,*Wr1,*br1,*Wc1,*bc1,*Wg1,*bg1,*Wp1,*bp1;
    float *r00,*r01,*h00,*h01,*rh0,*hg0;
    float *r10,*r11,*h10,*h11,*rh1,*hg1;
    unsigned* flags;
};

// Dual-layer persistent kernel. Blocks 0-127: layer0 (t = s), 128-255: layer1 (t = s-2).
// Block owns 4 columns x 64 batches; weights fp32 LDS-resident, read as wave-uniform
// b128 broadcasts. 3 grid-barrier phases/step; x-projections in barrier windows.
__global__ __launch_bounds__(NTHR) void esn_dual_k(KParams P)
{
    extern __shared__ char smem[];
    const int tid  = threadIdx.x;
    const int lane = tid & 63;
    const int wv   = tid >> 6;
    const int bid  = blockIdx.x;
    const int role = bid >> 7;
    const int c0   = (bid & 127) * 4;
    const int lin  = role ? Hf : INF;
    const int lin16 = lin >> 4;

    const float* Win  = role ? P.Win1  : P.Win0;
    const float* Wres = role ? P.Wres1 : P.Wres0;
    const float* Wz   = role ? P.Wz1   : P.Wz0;
    const float* bz   = role ? P.bz1   : P.bz0;
    const float* Wr   = role ? P.Wr1   : P.Wr0;
    const float* br   = role ? P.br1   : P.br0;
    const float* Wc   = role ? P.Wc1   : P.Wc0;
    const float* bc   = role ? P.bc1   : P.bc0;
    const float* Wg   = role ? P.Wg1   : P.Wg0;
    const float* bg   = role ? P.bg1   : P.bg0;
    const float* Wp   = role ? P.Wp1   : P.Wp0;
    const float* bp   = role ? P.bp1   : P.bp0;
    const float* xsrc = role ? P.y0    : P.xT0;
    float* r0 = role ? P.r10 : P.r00;
    float* r1 = role ? P.r11 : P.r01;
    float* h0 = role ? P.h10 : P.h00;
    float* h1 = role ? P.h11 : P.h01;
    float* rhB = role ? P.rh1 : P.rh0;
    float* hgB = role ? P.hg1 : P.hg0;

    // ---- LDS layout
    float4* sW = (float4*)smem;
    float4* wRESx = sW;              // lin rows
    float4* wRESs = wRESx + lin;     // 512
    float4* wZx   = wRESs + 512;     // lin
    float4* wZs   = wZx + lin;       // 512
    float4* wRx   = wZs + 512;       // lin
    float4* wRs   = wRx + lin;       // 512
    float4* wCx   = wRs + 512;       // lin
    float4* wCs   = wCx + lin;       // 512
    float4* wGx   = wCs + 512;       // lin
    float4* wGh   = wGx + lin;       // 512
    float4* wGr   = wGh + 512;       // 512
    float4* wP    = wGr + 512;       // 512
    float* pb  = (float*)(smem + (size_t)(5 * lin + 3584) * 16); // [3][4][16][64]
    float* lz  = pb + 12288;
    float* lp  = lz + 256;
    float* lgg = lp + 256;
    float* lhg = lgg + 256;

    // ---- stage this block's 4 columns of every matrix into LDS
    for (int k = tid; k < lin; k += NTHR) {
        wRESx[k] = *(const float4*)&Win[(size_t)k * 512 + c0];
        wZx[k]   = *(const float4*)&Wz[(size_t)k * 512 + c0];
        wRx[k]   = *(const float4*)&Wr[(size_t)k * 512 + c0];
        wCx[k]   = *(const float4*)&Wc[(size_t)k * 512 + c0];
        wGx[k]   = *(const float4*)&Wg[(size_t)k * 512 + c0];
    }
    for (int k = tid; k < 512; k += NTHR) {
        wRESs[k] = *(const float4*)&Wres[(size_t)k * 512 + c0];
        wZs[k]   = *(const float4*)&Wz[(size_t)(lin + k) * 512 + c0];
        wRs[k]   = *(const float4*)&Wr[(size_t)(lin + k) * 512 + c0];
        wCs[k]   = *(const float4*)&Wc[(size_t)(lin + k) * 512 + c0];
        wGh[k]   = *(const float4*)&Wg[(size_t)(lin + k) * 512 + c0];
        wGr[k]   = *(const float4*)&Wg[(size_t)(lin + 512 + k) * 512 + c0];
        wP[k]    = *(const float4*)&Wp[(size_t)k * 512 + c0];
    }
    __syncthreads();

    // reduce-thread identity (tid < 768; phase C uses tid < 256)
    const int m    = tid >> 8;
    const int rrem = tid & 255;
    const int cdx  = rrem >> 6;
    const int rbb  = rrem & 63;
    const int cab  = c0 + cdx;
    const int gi   = cab * 64 + rbb;
    float bzr = 0, brr = 0, bcr = 0, bpr = 0, bgr = 0;
    if (tid < 768) {
        bzr = bz[cab]; brr = br[cab]; bcr = bc[cab]; bpr = bp[cab]; bgr = bg[cab];
    }

#define PB_WRITE(mm, v) { \
    pb[(((mm)*4+0)*16+wv)*64+lane] = (v).x; \
    pb[(((mm)*4+1)*16+wv)*64+lane] = (v).y; \
    pb[(((mm)*4+2)*16+wv)*64+lane] = (v).z; \
    pb[(((mm)*4+3)*16+wv)*64+lane] = (v).w; }

    auto rsum = [&](int mm) -> float {
        float s2 = 0.f;
#pragma unroll
        for (int w = 0; w < 16; ++w) s2 += pb[((mm * 4 + cdx) * 16 + w) * 64 + rbb];
        return s2;
    };

    unsigned gen = 0;
    float4 z4 = {0.f, 0.f, 0.f, 0.f};
    float4 cRES = z4, cZ = z4, cR = z4, cX = z4, cG = z4;

    // prologue: layer-0 carries for t=0 (xT0 ready via kernel boundary)
    if (role == 0) xw3(xsrc, lane, wv, lin16, wRESx, wZx, wRx, cRES, cZ, cR);

    for (int s = 0; s < SGLOB; ++s) {
        const int t = role ? (s - 2) : s;
        const bool act = (t >= 0) && (t < Tt);
        const bool wn  = (t + 1 >= 0) && (t + 1 < Tt);
        float* rc = (t & 1) ? r1 : r0;
        float* rn = (t & 1) ? r0 : r1;
        float* hc = (t & 1) ? h1 : h0;
        float* hn = (t & 1) ? h0 : h1;
        const float* xs_t = xsrc + (size_t)(act ? t : 0) * lin * 64;
        const float* xs_n = xsrc + (size_t)(wn ? (t + 1) : 0) * lin * 64;

        // ================= phase A: r_new, z, rh =================
        wait_(P.flags, gen);
        fence_acq();
        if (act) {
            float ownR = 0.f, ownH = 0.f;
            if (tid < 768) { if (m == 0) ownR = rc[gi]; else if (m == 2) ownH = hc[gi]; }
            float4 aRES = cRES, aZ = cZ, aR = cR;
            const int ks = wv * 32;
#pragma unroll 8
            for (int k = ks; k < ks + 32; ++k) {
                float rv = rc[(size_t)k * 64 + lane];
                float hv = hc[(size_t)k * 64 + lane];
                float4 w;
                w = wRESs[k]; FMA4(aRES, w, rv);
                w = wZs[k];   FMA4(aZ, w, hv);
                w = wRs[k];   FMA4(aR, w, hv);
            }
            PB_WRITE(0, aRES); PB_WRITE(1, aZ); PB_WRITE(2, aR);
            __syncthreads();
            if (tid < 768) {
                float sa = rsum(m);
                if (m == 0)      stc(rn + gi, 0.7f * ownR + 0.3f * tanhf_(sa));
                else if (m == 1) lz[rrem] = sigmoidf_(sa + bzr);
                else             stc(rhB + gi, sigmoidf_(sa + brr) * ownH);
            }
        }
        arrive_(P.flags, ++gen);
        if (act) { cX = z4; cG = z4; xw2(xs_t, lane, wv, lin16, wCx, wGx, cX, cG); }

        // ================= phase B: h_gru, p, gg =================
        wait_(P.flags, gen);
        fence_acq();
        if (act) {
            float ownH = 0.f;
            if (tid < 768 && m == 0) ownH = hc[gi];
            float4 aC = cX, aP = z4, aG = cG;
            const int ks = wv * 32;
#pragma unroll 8
            for (int k = ks; k < ks + 32; ++k) {
                float rnv = rn[(size_t)k * 64 + lane];
                float rhv = rhB[(size_t)k * 64 + lane];
                float4 w;
                w = wCs[k]; FMA4(aC, w, rhv);
                w = wP[k];  FMA4(aP, w, rnv);
                w = wGr[k]; FMA4(aG, w, rnv);
            }
            PB_WRITE(0, aC); PB_WRITE(1, aP); PB_WRITE(2, aG);
            __syncthreads();
            if (tid < 768) {
                float sa = rsum(m);
                if (m == 0) {
                    float cand = tanhf_(sa + bcr);
                    float zv = lz[rrem];
                    float hg = (1.f - zv) * ownH + zv * cand;
                    stc(hgB + gi, hg);
                    lhg[rrem] = hg;
                } else if (m == 1) {
                    lp[rrem] = tanhf_(sa + bpr);
                } else {
                    lgg[rrem] = sa;
                }
            }
        }
        arrive_(P.flags, ++gen);
        if (wn) { cRES = z4; xw1(xs_n, lane, wv, lin16, wRESx, cRES); }

        // ================= phase C: g, h_new =================
        wait_(P.flags, gen);
        fence_acq();
        if (act) {
            float4 aGh = z4;
            const int ks = wv * 32;
#pragma unroll 8
            for (int k = ks; k < ks + 32; ++k) {
                float hgv = hgB[(size_t)k * 64 + lane];
                float4 w = wGh[k]; FMA4(aGh, w, hgv);
            }
            PB_WRITE(0, aGh);
            __syncthreads();
            if (tid < 256) {
                float sa = rsum(0);
                float g = sigmoidf_(sa + lgg[rrem] + bgr);
                float hnv = (1.f - g) * lhg[rrem] + g * lp[rrem];
                stc(hn + gi, hnv);
                if (role == 0) stc(P.y0 + (size_t)t * (Hf * 64) + gi, hnv);
            }
        }
        arrive_(P.flags, ++gen);
        if (wn) { cZ = z4; cR = z4; xw2(xs_n, lane, wv, lin16, wZx, wRx, cZ, cR); }
    }
#undef PB_WRITE
}

// Head: hid = relu(last@Wo1 + bo1)
__global__ __launch_bounds__(256) void head1_k(const float* __restrict__ hlast,
                                               const float* __restrict__ Wo1,
                                               const float* __restrict__ bo1,
                                               float* __restrict__ hidT) {
    int tid = threadIdx.x;
    int b = tid & 63, jg = tid >> 6;
    int j0 = blockIdx.x * 16 + jg * 4;
    float acc[4] = {0.f, 0.f, 0.f, 0.f};
    const float* ap = hlast + b;
    const float* wp = Wo1 + j0;
#pragma unroll 4
    for (int k = 0; k < Hf; ++k) {
        float xv = ap[k * 64];
        const float4 w = *reinterpret_cast<const float4*>(wp + k * 512);
        acc[0] = fmaf(w.x, xv, acc[0]);
        acc[1] = fmaf(w.y, xv, acc[1]);
        acc[2] = fmaf(w.z, xv, acc[2]);
        acc[3] = fmaf(w.w, xv, acc[3]);
    }
#pragma unroll
    for (int jj = 0; jj < 4; ++jj) {
        int j = j0 + jj;
        hidT[j * 64 + b] = fmaxf(acc[jj] + bo1[j], 0.f);
    }
}

__global__ __launch_bounds__(640) void head2_k(const float* __restrict__ hidT,
                                               const float* __restrict__ Wo2,
                                               const float* __restrict__ bo2,
                                               float* __restrict__ out) {
    int tid = threadIdx.x;
    if (tid >= 64 * OUTF) return;
    int b = tid / OUTF, o = tid % OUTF;
    float acc = 0.f;
    for (int k = 0; k < Hf; ++k)
        acc = fmaf(hidT[k * 64 + b], Wo2[k * OUTF + o], acc);
    out[tid] = acc + bo2[o];
}

extern "C" void kernel_launch(void* const* d_in, const int* in_sizes, int n_in,
                              void* d_out, int out_size, void* d_ws, size_t ws_size,
                              hipStream_t stream) {
    const float* x = (const float*)d_in[0];
    const float* W[2][12];
    int idx = 1;
    for (int li = 0; li < 2; ++li)
        for (int j = 0; j < 12; ++j) W[li][j] = (const float*)d_in[idx++];
    const float* Wo1 = (const float*)d_in[idx++];
    const float* bo1 = (const float*)d_in[idx++];
    const float* Wo2 = (const float*)d_in[idx++];
    const float* bo2 = (const float*)d_in[idx++];

    char* ws = (char*)d_ws;
    size_t off = 0;
    auto walloc = [&](size_t bytes) -> float* {
        float* p = (float*)(ws + off);
        off += (bytes + 255) & ~(size_t)255;
        return p;
    };
    const size_t STATE = (size_t)Hf * 64 * sizeof(float); // 128 KiB
    float* xT0 = walloc((size_t)Tt * INF * 64 * sizeof(float)); // 33.5 MB
    float* y0  = walloc((size_t)Tt * Hf * 64 * sizeof(float));  // 67 MB
    KParams P;
    P.xT0 = xT0; P.y0 = y0;
    P.Win0 = W[0][0]; P.Wres0 = W[0][1]; P.Wz0 = W[0][2]; P.bz0 = W[0][3];
    P.Wr0 = W[0][4]; P.br0 = W[0][5]; P.Wc0 = W[0][6]; P.bc0 = W[0][7];
    P.Wg0 = W[0][8]; P.bg0 = W[0][9]; P.Wp0 = W[0][10]; P.bp0 = W[0][11];
    P.Win1 = W[1][0]; P.Wres1 = W[1][1]; P.Wz1 = W[1][2]; P.bz1 = W[1][3];
    P.Wr1 = W[1][4]; P.br1 = W[1][5]; P.Wc1 = W[1][6]; P.bc1 = W[1][7];
    P.Wg1 = W[1][8]; P.bg1 = W[1][9]; P.Wp1 = W[1][10]; P.bp1 = W[1][11];
    P.r00 = walloc(STATE); P.r01 = walloc(STATE);
    P.h00 = walloc(STATE); P.h01 = walloc(STATE);
    P.rh0 = walloc(STATE); P.hg0 = walloc(STATE);
    P.r10 = walloc(STATE); P.r11 = walloc(STATE);
    P.h10 = walloc(STATE); P.h11 = walloc(STATE);
    P.rh1 = walloc(STATE); P.hg1 = walloc(STATE);
    float* hidT = walloc(STATE);
    P.flags = (unsigned*)walloc(NBLK * sizeof(unsigned));
    (void)ws_size;

    hipFuncSetAttribute((const void*)esn_dual_k,
                        hipFuncAttributeMaxDynamicSharedMemorySize, SMEM_BYTES);

    transpose_x_k<<<dim3(Tt, INF / 64), 256, 0, stream>>>(x, xT0);

    hipMemsetAsync(P.flags, 0, NBLK * sizeof(unsigned), stream);
    hipMemsetAsync(P.r00, 0, STATE, stream);
    hipMemsetAsync(P.h00, 0, STATE, stream);
    hipMemsetAsync(P.r10, 0, STATE, stream);
    hipMemsetAsync(P.h10, 0, STATE, stream);

    esn_dual_k<<<NBLK, NTHR, SMEM_BYTES, stream>>>(P);

    // t=511 (odd) wrote buffer 0 -> layer-1 final h is in h10.
    head1_k<<<dim3(32, 1), 256, 0, stream>>>(P.h10, Wo1, bo1, hidT);
    head2_k<<<dim3(1, 1), 640, 0, stream>>>(hidT, Wo2, bo2, (float*)d_out);
}

// Round 7
// 37521.689 us; speedup vs baseline: 1.8228x; 1.6914x over previous
//
#include <hip/hip_runtime.h>
#include <math.h>

static constexpr int Tt   = 512;
static constexpr int INF  = 256;
static constexpr int Hf   = 512;
static constexpr int OUTF = 10;
static constexpr int NBLK = 256;   // 128 layer-0 blocks + 128 layer-1 blocks
static constexpr int NTHR = 1024;  // 16 waves
static constexpr int SGLOB = Tt + 2;
static constexpr unsigned SMEM_BYTES = 98304 + 49152 + 4096; // weights + pb + locals

__device__ __forceinline__ float sigmoidf_(float x) {
    return 1.0f / (1.0f + __expf(-x));
}
__device__ __forceinline__ float tanhf_(float x) {
    float e = __expf(-2.0f * fabsf(x));
    float r = (1.0f - e) / (1.0f + e);
    return copysignf(r, x);
}

// 4-byte scope-coherent access: LLC-served, cached, no fences (round-3-proven).
__device__ __forceinline__ float ldc(const float* p) {
    return __hip_atomic_load(const_cast<float*>(p), __ATOMIC_RELAXED, __HIP_MEMORY_SCOPE_AGENT);
}
__device__ __forceinline__ void stc(float* p, float v) {
    __hip_atomic_store(p, v, __ATOMIC_RELAXED, __HIP_MEMORY_SCOPE_AGENT);
}

// Grid barrier: arrive (drain stores -> block barrier -> flag), wait (poll flags).
__device__ __forceinline__ void arrive_(unsigned* flags, unsigned gen) {
    asm volatile("s_waitcnt vmcnt(0)" ::: "memory");
    __syncthreads();
    if (threadIdx.x == 0)
        __hip_atomic_store(&flags[blockIdx.x], gen, __ATOMIC_RELAXED, __HIP_MEMORY_SCOPE_AGENT);
}
__device__ __forceinline__ void wait_(unsigned* flags, unsigned gen) {
    if (threadIdx.x < NBLK) {
        unsigned* f = &flags[threadIdx.x];
        while (__hip_atomic_load(f, __ATOMIC_RELAXED, __HIP_MEMORY_SCOPE_AGENT) < gen)
            __builtin_amdgcn_s_sleep(1);
    }
    __syncthreads();
}

// x (B,T,IN) -> xT (T,IN,B)
__global__ __launch_bounds__(256) void transpose_x_k(const float* __restrict__ x,
                                                     float* __restrict__ xT) {
    __shared__ float tile[64][65];
    int t  = blockIdx.x;
    int k0 = blockIdx.y * 64;
    int tid = threadIdx.x;
#pragma unroll
    for (int i = 0; i < 16; ++i) {
        int idx = i * 256 + tid;
        int bb = idx >> 6, kk = idx & 63;
        tile[bb][kk] = x[(size_t)bb * Tt * INF + (size_t)t * INF + k0 + kk];
    }
    __syncthreads();
#pragma unroll
    for (int i = 0; i < 16; ++i) {
        int idx = i * 256 + tid;
        int kk = idx >> 6, bb = idx & 63;
        xT[(size_t)t * INF * 64 + (size_t)(k0 + kk) * 64 + bb] = tile[bb][kk];
    }
}

#define FMA4(a, w, v) { (a).x = fmaf((w).x, (v), (a).x); (a).y = fmaf((w).y, (v), (a).y); \
                        (a).z = fmaf((w).z, (v), (a).z); (a).w = fmaf((w).w, (v), (a).w); }

template<bool SC>
__device__ __forceinline__ float ldx(const float* p) { return SC ? ldc(p) : *p; }

// x-projection windows: prefetch x slice to regs, LDS weight broadcast.
template<int L16, bool SC>
__device__ __forceinline__ void xw2(const float* xs, int lane, int wv,
                                    const float4* w0, const float4* w1,
                                    float4& a0, float4& a1) {
    const int kb = wv * L16;
    float xv[L16];
#pragma unroll
    for (int i = 0; i < L16; ++i) xv[i] = ldx<SC>(xs + (size_t)(kb + i) * 64 + lane);
#pragma unroll
    for (int i = 0; i < L16; ++i) {
        float4 w = w0[kb + i]; FMA4(a0, w, xv[i]);
        w = w1[kb + i];        FMA4(a1, w, xv[i]);
    }
}
template<int L16, bool SC>
__device__ __forceinline__ void xw3(const float* xs, int lane, int wv,
                                    const float4* w0, const float4* w1, const float4* w2,
                                    float4& a0, float4& a1, float4& a2) {
    const int kb = wv * L16;
    float xv[L16];
#pragma unroll
    for (int i = 0; i < L16; ++i) xv[i] = ldx<SC>(xs + (size_t)(kb + i) * 64 + lane);
#pragma unroll
    for (int i = 0; i < L16; ++i) {
        float4 w = w0[kb + i]; FMA4(a0, w, xv[i]);
        w = w1[kb + i];        FMA4(a1, w, xv[i]);
        w = w2[kb + i];        FMA4(a2, w, xv[i]);
    }
}

// One layer's persistent loop (inlined per role; LIN compile-time).
template<int LIN, bool XSC, bool WY>
__device__ __forceinline__ void run_layer(
    const float* __restrict__ xsrc, float* y0,
    float* r0, float* r1, float* h0, float* h1, float* rhB, float* hgB,
    const float* __restrict__ Win, const float* __restrict__ Wres,
    const float* __restrict__ Wz, const float* __restrict__ bz,
    const float* __restrict__ Wr, const float* __restrict__ br,
    const float* __restrict__ Wc, const float* __restrict__ bc,
    const float* __restrict__ Wg, const float* __restrict__ bg,
    const float* __restrict__ Wp, const float* __restrict__ bp,
    unsigned* flags, int c0, int tshift)
{
    constexpr int L16 = LIN / 16;
    extern __shared__ char smem[];
    float4* wRESx = (float4*)smem;   // LIN
    float4* wRESs = wRESx + LIN;     // 512
    float4* wZx   = wRESs + 512;     // LIN
    float4* wZs   = wZx + LIN;       // 512
    float4* wRx   = wZs + 512;       // LIN
    float4* wRs   = wRx + LIN;       // 512
    float4* wCx   = wRs + 512;       // LIN
    float4* wCs   = wCx + LIN;       // 512
    float4* wGx   = wCs + 512;       // LIN
    float4* wGh   = wGx + LIN;       // 512
    float4* wGr   = wGh + 512;       // 512
    float4* wP    = wGr + 512;       // 512
    float* pb  = (float*)(smem + (size_t)(5 * LIN + 3584) * 16); // [3][4][16][64]
    float* lz  = pb + 12288;
    float* lp  = lz + 256;
    float* lgg = lp + 256;
    float* lhg = lgg + 256;

    const int tid  = threadIdx.x;
    const int lane = tid & 63;
    const int wv   = tid >> 6;

    // ---- stage this block's 4 columns of every matrix into LDS
    for (int k = tid; k < LIN; k += NTHR) {
        wRESx[k] = *(const float4*)&Win[(size_t)k * 512 + c0];
        wZx[k]   = *(const float4*)&Wz[(size_t)k * 512 + c0];
        wRx[k]   = *(const float4*)&Wr[(size_t)k * 512 + c0];
        wCx[k]   = *(const float4*)&Wc[(size_t)k * 512 + c0];
        wGx[k]   = *(const float4*)&Wg[(size_t)k * 512 + c0];
    }
    for (int k = tid; k < 512; k += NTHR) {
        wRESs[k] = *(const float4*)&Wres[(size_t)k * 512 + c0];
        wZs[k]   = *(const float4*)&Wz[(size_t)(LIN + k) * 512 + c0];
        wRs[k]   = *(const float4*)&Wr[(size_t)(LIN + k) * 512 + c0];
        wCs[k]   = *(const float4*)&Wc[(size_t)(LIN + k) * 512 + c0];
        wGh[k]   = *(const float4*)&Wg[(size_t)(LIN + k) * 512 + c0];
        wGr[k]   = *(const float4*)&Wg[(size_t)(LIN + 512 + k) * 512 + c0];
        wP[k]    = *(const float4*)&Wp[(size_t)k * 512 + c0];
    }
    __syncthreads();

    // reduce-thread identity
    const int m    = tid >> 8;
    const int rrem = tid & 255;
    const int cdx  = rrem >> 6;
    const int rbb  = rrem & 63;
    const int cab  = c0 + cdx;
    const int gi   = cab * 64 + rbb;
    float bzr = 0, brr = 0, bcr = 0, bpr = 0, bgr = 0;
    if (tid < 768) {
        bzr = bz[cab]; brr = br[cab]; bcr = bc[cab]; bpr = bp[cab]; bgr = bg[cab];
    }

#define PB_WRITE(mm, v) { \
    pb[(((mm)*4+0)*16+wv)*64+lane] = (v).x; \
    pb[(((mm)*4+1)*16+wv)*64+lane] = (v).y; \
    pb[(((mm)*4+2)*16+wv)*64+lane] = (v).z; \
    pb[(((mm)*4+3)*16+wv)*64+lane] = (v).w; }

    unsigned gen = 0;
    const float4 z4 = {0.f, 0.f, 0.f, 0.f};
    float4 cRES = z4, cZ = z4, cR = z4, cX = z4, cG = z4;
    const int ks = wv * 32;

    // prologue: layer-0 carries for t=0
    if (tshift == 0)
        xw3<L16, XSC>(xsrc, lane, wv, wRESx, wZx, wRx, cRES, cZ, cR);

    for (int s = 0; s < SGLOB; ++s) {
        const int t = s - tshift;
        const bool act = (t >= 0) && (t < Tt);
        const bool wn  = (t + 1 >= 0) && (t + 1 < Tt);
        float* rc = (t & 1) ? r1 : r0;
        float* rn = (t & 1) ? r0 : r1;
        float* hc = (t & 1) ? h1 : h0;
        float* hn = (t & 1) ? h0 : h1;
        const float* xs_t = xsrc + (size_t)(act ? t : 0) * LIN * 64;
        const float* xs_n = xsrc + (size_t)(wn ? (t + 1) : 0) * LIN * 64;

        // ================= phase A: r_new, z, rh =================
        wait_(flags, gen);
        if (act) {
            float ownR = 0.f, ownH = 0.f;
            if (tid < 768) { if (m == 0) ownR = ldc(rc + gi); else if (m == 2) ownH = ldc(hc + gi); }
            float rv[32], hv[32];
#pragma unroll
            for (int i = 0; i < 32; ++i) rv[i] = ldc(rc + (size_t)(ks + i) * 64 + lane);
#pragma unroll
            for (int i = 0; i < 32; ++i) hv[i] = ldc(hc + (size_t)(ks + i) * 64 + lane);
            float4 aRES = cRES, aZ = cZ, aR = cR;
#pragma unroll
            for (int i = 0; i < 32; ++i) { float4 w = wRESs[ks + i]; FMA4(aRES, w, rv[i]); }
#pragma unroll
            for (int i = 0; i < 32; ++i) {
                float4 w = wZs[ks + i]; FMA4(aZ, w, hv[i]);
                w = wRs[ks + i];        FMA4(aR, w, hv[i]);
            }
            PB_WRITE(0, aRES); PB_WRITE(1, aZ); PB_WRITE(2, aR);
            __syncthreads();
            if (tid < 768) {
                float sa = 0.f;
#pragma unroll
                for (int w = 0; w < 16; ++w) sa += pb[((m * 4 + cdx) * 16 + w) * 64 + rbb];
                if (m == 0)      stc(rn + gi, 0.7f * ownR + 0.3f * tanhf_(sa));
                else if (m == 1) lz[rrem] = sigmoidf_(sa + bzr);
                else             stc(rhB + gi, sigmoidf_(sa + brr) * ownH);
            }
        }
        arrive_(flags, ++gen);
        if (act) { cX = z4; cG = z4; xw2<L16, XSC>(xs_t, lane, wv, wCx, wGx, cX, cG); }
        wait_(flags, gen);

        // ================= phase B: h_gru, p, gg =================
        if (act) {
            float ownH = 0.f;
            if (tid < 768 && m == 0) ownH = ldc(hc + gi);
            float rnv[32], rhv[32];
#pragma unroll
            for (int i = 0; i < 32; ++i) rnv[i] = ldc(rn + (size_t)(ks + i) * 64 + lane);
#pragma unroll
            for (int i = 0; i < 32; ++i) rhv[i] = ldc(rhB + (size_t)(ks + i) * 64 + lane);
            float4 aC = cX, aP = z4, aG = cG;
#pragma unroll
            for (int i = 0; i < 32; ++i) {
                float4 w = wP[ks + i];  FMA4(aP, w, rnv[i]);
                w = wGr[ks + i];        FMA4(aG, w, rnv[i]);
            }
#pragma unroll
            for (int i = 0; i < 32; ++i) { float4 w = wCs[ks + i]; FMA4(aC, w, rhv[i]); }
            PB_WRITE(0, aC); PB_WRITE(1, aP); PB_WRITE(2, aG);
            __syncthreads();
            if (tid < 768) {
                float sa = 0.f;
#pragma unroll
                for (int w = 0; w < 16; ++w) sa += pb[((m * 4 + cdx) * 16 + w) * 64 + rbb];
                if (m == 0) {
                    float cand = tanhf_(sa + bcr);
                    float zv = lz[rrem];
                    float hg = (1.f - zv) * ownH + zv * cand;
                    stc(hgB + gi, hg);
                    lhg[rrem] = hg;
                } else if (m == 1) {
                    lp[rrem] = tanhf_(sa + bpr);
                } else {
                    lgg[rrem] = sa;
                }
            }
        }
        arrive_(flags, ++gen);
        if (wn) { cRES = z4; cZ = z4; cR = z4;
                  xw3<L16, XSC>(xs_n, lane, wv, wRESx, wZx, wRx, cRES, cZ, cR); }
        wait_(flags, gen);

        // ================= phase C: g, h_new =================
        if (act) {
            float hgv[32];
#pragma unroll
            for (int i = 0; i < 32; ++i) hgv[i] = ldc(hgB + (size_t)(ks + i) * 64 + lane);
            float4 aGh = z4;
#pragma unroll
            for (int i = 0; i < 32; ++i) { float4 w = wGh[ks + i]; FMA4(aGh, w, hgv[i]); }
            PB_WRITE(0, aGh);
            __syncthreads();
            if (tid < 256) {
                float sa = 0.f;
#pragma unroll
                for (int w = 0; w < 16; ++w) sa += pb[((cdx) * 16 + w) * 64 + rbb];
                float g = sigmoidf_(sa + lgg[rrem] + bgr);
                float hnv = (1.f - g) * lhg[rrem] + g * lp[rrem];
                stc(hn + gi, hnv);
                if (WY) stc(y0 + (size_t)t * (Hf * 64) + gi, hnv);
            }
        }
        arrive_(flags, ++gen);
    }
#undef PB_WRITE
}

struct KParams {
    const float* xT0;
    float* y0;
    const float *Win0,*Wres0,*Wz0,*bz0,*Wr0,*br0,*Wc0,*bc0,*Wg0,*bg0,*Wp0,*bp0;
    const float *Win1,*Wres1,*Wz1,*bz1,*Wr1,*br1,*Wc1,*bc1,*Wg1,*bg1,*Wp1,*bp1;
    float *r00,*r01,*h00,*h01,*rh0,*hg0;
    float *r10,*r11,*h10,*h11,*rh1,*hg1;
    unsigned* flags;
};

// Dual-layer persistent kernel. Blocks 0-127: layer0 (t=s), 128-255: layer1 (t=s-2).
__global__ __launch_bounds__(NTHR) void esn_dual_k(KParams P)
{
    const int bid = blockIdx.x;
    const int c0  = (bid & 127) * 4;
    if (bid < 128) {
        run_layer<INF, false, true>(P.xT0, P.y0,
            P.r00, P.r01, P.h00, P.h01, P.rh0, P.hg0,
            P.Win0, P.Wres0, P.Wz0, P.bz0, P.Wr0, P.br0,
            P.Wc0, P.bc0, P.Wg0, P.bg0, P.Wp0, P.bp0,
            P.flags, c0, 0);
    } else {
        run_layer<Hf, true, false>(P.y0, nullptr,
            P.r10, P.r11, P.h10, P.h11, P.rh1, P.hg1,
            P.Win1, P.Wres1, P.Wz1, P.bz1, P.Wr1, P.br1,
            P.Wc1, P.bc1, P.Wg1, P.bg1, P.Wp1, P.bp1,
            P.flags, c0, 2);
    }
}

// Head: hid = relu(last@Wo1 + bo1)
__global__ __launch_bounds__(256) void head1_k(const float* __restrict__ hlast,
                                               const float* __restrict__ Wo1,
                                               const float* __restrict__ bo1,
                                               float* __restrict__ hidT) {
    int tid = threadIdx.x;
    int b = tid & 63, jg = tid >> 6;
    int j0 = blockIdx.x * 16 + jg * 4;
    float acc[4] = {0.f, 0.f, 0.f, 0.f};
    const float* ap = hlast + b;
    const float* wp = Wo1 + j0;
#pragma unroll 4
    for (int k = 0; k < Hf; ++k) {
        float xv = ap[k * 64];
        const float4 w = *reinterpret_cast<const float4*>(wp + k * 512);
        acc[0] = fmaf(w.x, xv, acc[0]);
        acc[1] = fmaf(w.y, xv, acc[1]);
        acc[2] = fmaf(w.z, xv, acc[2]);
        acc[3] = fmaf(w.w, xv, acc[3]);
    }
#pragma unroll
    for (int jj = 0; jj < 4; ++jj) {
        int j = j0 + jj;
        hidT[j * 64 + b] = fmaxf(acc[jj] + bo1[j], 0.f);
    }
}

__global__ __launch_bounds__(640) void head2_k(const float* __restrict__ hidT,
                                               const float* __restrict__ Wo2,
                                               const float* __restrict__ bo2,
                                               float* __restrict__ out) {
    int tid = threadIdx.x;
    if (tid >= 64 * OUTF) return;
    int b = tid / OUTF, o = tid % OUTF;
    float acc = 0.f;
    for (int k = 0; k < Hf; ++k)
        acc = fmaf(hidT[k * 64 + b], Wo2[k * OUTF + o], acc);
    out[tid] = acc + bo2[o];
}

extern "C" void kernel_launch(void* const* d_in, const int* in_sizes, int n_in,
                              void* d_out, int out_size, void* d_ws, size_t ws_size,
                              hipStream_t stream) {
    const float* x = (const float*)d_in[0];
    const float* W[2][12];
    int idx = 1;
    for (int li = 0; li < 2; ++li)
        for (int j = 0; j < 12; ++j) W[li][j] = (const float*)d_in[idx++];
    const float* Wo1 = (const float*)d_in[idx++];
    const float* bo1 = (const float*)d_in[idx++];
    const float* Wo2 = (const float*)d_in[idx++];
    const float* bo2 = (const float*)d_in[idx++];

    char* ws = (char*)d_ws;
    size_t off = 0;
    auto walloc = [&](size_t bytes) -> float* {
        float* p = (float*)(ws + off);
        off += (bytes + 255) & ~(size_t)255;
        return p;
    };
    const size_t STATE = (size_t)Hf * 64 * sizeof(float); // 128 KiB
    float* xT0 = walloc((size_t)Tt * INF * 64 * sizeof(float)); // 33.5 MB
    float* y0  = walloc((size_t)Tt * Hf * 64 * sizeof(float));  // 67 MB
    KParams P;
    P.xT0 = xT0; P.y0 = y0;
    P.Win0 = W[0][0]; P.Wres0 = W[0][1]; P.Wz0 = W[0][2]; P.bz0 = W[0][3];
    P.Wr0 = W[0][4]; P.br0 = W[0][5]; P.Wc0 = W[0][6]; P.bc0 = W[0][7];
    P.Wg0 = W[0][8]; P.bg0 = W[0][9]; P.Wp0 = W[0][10]; P.bp0 = W[0][11];
    P.Win1 = W[1][0]; P.Wres1 = W[1][1]; P.Wz1 = W[1][2]; P.bz1 = W[1][3];
    P.Wr1 = W[1][4]; P.br1 = W[1][5]; P.Wc1 = W[1][6]; P.bc1 = W[1][7];
    P.Wg1 = W[1][8]; P.bg1 = W[1][9]; P.Wp1 = W[1][10]; P.bp1 = W[1][11];
    P.r00 = walloc(STATE); P.r01 = walloc(STATE);
    P.h00 = walloc(STATE); P.h01 = walloc(STATE);
    P.rh0 = walloc(STATE); P.hg0 = walloc(STATE);
    P.r10 = walloc(STATE); P.r11 = walloc(STATE);
    P.h10 = walloc(STATE); P.h11 = walloc(STATE);
    P.rh1 = walloc(STATE); P.hg1 = walloc(STATE);
    float* hidT = walloc(STATE);
    P.flags = (unsigned*)walloc(NBLK * sizeof(unsigned));
    (void)ws_size;

    hipFuncSetAttribute((const void*)esn_dual_k,
                        hipFuncAttributeMaxDynamicSharedMemorySize, SMEM_BYTES);

    transpose_x_k<<<dim3(Tt, INF / 64), 256, 0, stream>>>(x, xT0);

    hipMemsetAsync(P.flags, 0, NBLK * sizeof(unsigned), stream);
    hipMemsetAsync(P.r00, 0, STATE, stream);
    hipMemsetAsync(P.h00, 0, STATE, stream);
    hipMemsetAsync(P.r10, 0, STATE, stream);
    hipMemsetAsync(P.h10, 0, STATE, stream);

    esn_dual_k<<<NBLK, NTHR, SMEM_BYTES, stream>>>(P);

    // t=511 (odd) wrote buffer 0 -> layer-1 final h is in h10.
    head1_k<<<dim3(32, 1), 256, 0, stream>>>(P.h10, Wo1, bo1, hidT);
    head2_k<<<dim3(1, 1), 640, 0, stream>>>(hidT, Wo2, bo2, (float*)d_out);
}